// Round 11
// baseline (381.186 us; speedup 1.0000x reference)
//
#include <hip/hip_runtime.h>
#include <hip/hip_fp16.h>

// ---------------------------------------------------------------------------
// GCN (3 layers) + global mean pool + linear, fp32 in/out, MI355X.
// t'[i] = dinv[i] * h[i] W^T; h_next[i] = relu(dinv[i]*(t'[i]+sum t'[j]) + b)
// R3-R5: scattered 4B stores/atomics = ~32B HBM sector each. Dense only.
// R9: fp16 t (128B row = 1 L2 line), absmax 1.2e-4.
// R20/R23/R24: compiler refuses >8-deep load windows (16 dest VGPRs max).
// R25: L2 half-tiling FAILED; gather NOT miss-bound.
// R26: occupancy ANTI-correlated w/ barriers; straggler coupling governs.
// R27 (WIN): no-__syncthreads aggmm (wave-private LDS rows). 280.67.
// R28 (split): 16B/lane uint4 gather: aggmm 54.6->~51 WIN (rounds 4->2);
//   aggfinal REGRESS (slice already 1-round; widening = masked waste).
// R29 (WIN, 278.6): aggfinal 16B/lane with 8-edge rounds -> ~42us.
// R30 (this round): aggmm 512->256 thr (16 nodes, 4 waves, grid 3125),
//   launch_bounds(256,8). Mechanism: zero-barrier blocks still retain
//   resources until the SLOWEST wave retires (occupancy 29.6% despite
//   VGPR/LDS headroom) -> halve retention granule (max-of-4 vs max-of-8
//   Poisson stragglers), 2x more independently-retiring blocks/CU.
// ---------------------------------------------------------------------------

#define CAPB 3072
#define BINTILE 4096

// fctr zero + per-graph inverse counts (binary search on sorted batch) +
// out seeded with bl (aggfinal accumulates atomically on top).
__global__ __launch_bounds__(256) void init_kernel(int* __restrict__ fctr,
                                                   const int* __restrict__ batch,
                                                   const float* __restrict__ bl,
                                                   float* __restrict__ invc,
                                                   float* __restrict__ out,
                                                   int n, int nb) {
    int t = blockIdx.x * blockDim.x + threadIdx.x;
    if (t < 512) fctr[t] = 0;
    if (t < nb) {
        int l = 0, r = n;
        while (l < r) { int m = (l + r) >> 1; if (batch[m] < t) l = m + 1; else r = m; }
        int lo = l;
        r = n;
        while (l < r) { int m = (l + r) >> 1; if (batch[m] < t + 1) l = m + 1; else r = m; }
        invc[t] = 1.0f / fmaxf((float)(l - lo), 1.0f);
#pragma unroll
        for (int o = 0; o < 16; ++o) out[t * 16 + o] = bl[o];
    }
}

// Bucket edges into 512 fine dst-ranges (fixed capacity CAPB, base=g*CAPB).
__global__ __launch_bounds__(256) void bin512_kernel(const int* __restrict__ src,
                                                     const int* __restrict__ dst,
                                                     int* __restrict__ fctr,
                                                     int2* __restrict__ recs2,
                                                     int e, int n) {
    __shared__ int lcnt[512], gbase[512];
    int tid = threadIdx.x;
    int s0  = blockIdx.x * BINTILE;
    lcnt[tid] = 0;
    lcnt[tid + 256] = 0;
    __syncthreads();
    int dv[16], bk[16];
#pragma unroll
    for (int k = 0; k < 16; ++k) {
        int i = s0 + tid + k * 256;  // coalesced
        if (i < e) {
            dv[k] = dst[i];
            bk[k] = (int)((512LL * dv[k]) / n);
            atomicAdd(&lcnt[bk[k]], 1);
        } else {
            bk[k] = -1;
        }
    }
    __syncthreads();
#pragma unroll
    for (int j = 0; j < 2; ++j) {
        int b = tid + j * 256;
        gbase[b] = b * CAPB + atomicAdd(&fctr[b], lcnt[b]);
        lcnt[b]  = 0;  // reuse as placement counter
    }
    __syncthreads();
#pragma unroll
    for (int k = 0; k < 16; ++k) {
        if (bk[k] >= 0) {
            int i = s0 + tid + k * 256;
            int p = gbase[bk[k]] + atomicAdd(&lcnt[bk[k]], 1);
            if (p < (bk[k] + 1) * CAPB) recs2[p] = make_int2(src[i], dv[k]);
        }
    }
}

// One block per fine bucket: LDS counting sort -> dense csr, rp/dinv, then
// fused mm1 for this bucket's nodes: t1 = fp16(dinv * x W1^T).
__global__ __launch_bounds__(256) void sortfill_mm_kernel(
    const int2* __restrict__ recs2, const int* __restrict__ fctr,
    int* __restrict__ rp, float* __restrict__ dinv, int* __restrict__ csr,
    const float* __restrict__ x, const float* __restrict__ W1,
    __half* __restrict__ t1, int n) {
    __shared__ int hist[128];
    __shared__ int lofs[129];
    __shared__ int stage[CAPB];
    __shared__ int redbuf[256];
    __shared__ float xrow[98 * 64];  // 25KB
    int g   = blockIdx.x;
    int N0  = (int)(((long long)n * g + 511) / 512);
    int N1  = (int)(((long long)n * (g + 1) + 511) / 512);
    int nn  = N1 - N0;  // <= 98
    int tid = threadIdx.x;
    int lane = tid & 63;
    int wave = tid >> 6;

    int partial = 0;
    for (int j = tid; j < g; j += 256) partial += min(fctr[j], CAPB);
    redbuf[tid] = partial;
    if (tid < 128) hist[tid] = 0;
    __syncthreads();
    for (int s = 128; s > 0; s >>= 1) {
        if (tid < s) redbuf[tid] += redbuf[tid + s];
        __syncthreads();
    }
    int base = redbuf[0];
    const int2* my = recs2 + (size_t)g * CAPB;
    int total = min(fctr[g], CAPB);
    for (int i = tid; i < total; i += 256)
        atomicAdd(&hist[my[i].y - N0], 1);
    __syncthreads();
    if (tid == 0) {
        int acc = 0;
        for (int k = 0; k < nn; ++k) { lofs[k] = acc; acc += hist[k]; }
        lofs[nn] = acc;
    }
    __syncthreads();
    if (tid < 128) hist[tid] = 0;  // placement counters
    __syncthreads();
    for (int i = tid; i < total; i += 256) {
        int2 rec = my[i];
        int  li  = rec.y - N0;
        int  pos = lofs[li] + atomicAdd(&hist[li], 1);
        stage[pos] = rec.x;  // pos < total <= CAPB
    }
    __syncthreads();
    for (int j = tid; j < total; j += 256) csr[base + j] = stage[j];
    if (tid < nn) {
        rp[N0 + tid]   = base + lofs[tid];
        int deg        = lofs[tid + 1] - lofs[tid];
        dinv[N0 + tid] = rsqrtf((float)(deg + 1));
    }
    if (g == 511 && tid == 0) rp[n] = base + total;

    // ---- fused mm1 for this bucket's nodes ----
    for (int idx = tid; idx < nn * 16; idx += 256)
        ((float4*)xrow)[idx] = ((const float4*)(x + (size_t)N0 * 64))[idx];
    float4 wreg[16];
    const float4* W4 = (const float4*)(W1 + lane * 64);
#pragma unroll
    for (int q = 0; q < 16; ++q) wreg[q] = W4[q];
    __syncthreads();
    for (int li = wave; li < nn; li += 4) {
        float dv = rsqrtf((float)(lofs[li + 1] - lofs[li] + 1));
        const float4* row = (const float4*)(xrow + li * 64);
        float acc = 0.0f;
#pragma unroll
        for (int q = 0; q < 16; ++q) {
            float4 hv = row[q];  // wave-uniform -> LDS broadcast
            acc += hv.x * wreg[q].x + hv.y * wreg[q].y +
                   hv.z * wreg[q].z + hv.w * wreg[q].w;
        }
        t1[(size_t)(N0 + li) * 64 + lane] = __float2half(acc * dv);
    }
}

// Fused agg(layer k) + mm(layer k+1): 256 thr = 4 waves, 16 nodes/block
// (R30: halved retention granule). GATHER (R28): one node per 16-lane
// group, 16B/lane uint4, 2 edges per group-instr, 16-edge rounds (deg 25
// -> 2 rounds). shfl_xor(8) merges even/odd partials. h rows -> LDS
// wave-private rows 4w..4w+3, NO __syncthreads (R27).
// MM: W row per lane in 16 float4 regs (amortized over 4 rows/wave).
__global__ __launch_bounds__(256, 8) void aggmm_kernel(const __half* __restrict__ t,
                                                       const int* __restrict__ rp,
                                                       const int* __restrict__ cs,
                                                       const float* __restrict__ dinv,
                                                       const float* __restrict__ bias,
                                                       const float* __restrict__ W,
                                                       __half* __restrict__ tout, int n) {
    __shared__ float hs[16 * 64];  // 4KB, rows 4w..4w+3 private to wave w
    __shared__ float dvs[16];
    int tid  = threadIdx.x;
    int lane = tid & 63;
    int wave = tid >> 6;        // 0..3
    int g    = lane >> 4;       // group = node slot 0..3
    int sub  = (lane >> 3) & 1; // edge-parity slot within group
    int fo   = (lane & 7) << 3; // lane owns features fo..fo+7
    int base = blockIdx.x * 16;
    int nl   = wave * 4 + g;    // local node 0..15
    int i    = base + nl;

    float4 aA0 = make_float4(0.f, 0.f, 0.f, 0.f);
    float4 aA1 = aA0, aB0 = aA0, aB1 = aA0;
    float2 s0 = make_float2(0.f, 0.f), s1 = s0, s2 = s0, s3 = s0;
    float  dv = 1.0f;

    if (i < n) {
        int beg = rp[i];
        int end = rp[i + 1];
        uint4 su = *(const uint4*)(t + (size_t)i * 64 + fo);  // self row (early)
        dv = dinv[i];
        for (int eb = beg; eb < end; eb += 16) {
#pragma unroll
            for (int j = 0; j < 8; ++j) {
                int   ej = eb + 2 * j + sub;
                int   ec = min(ej, end - 1);         // in-bounds (loop => end>beg)
                int   sj = cs[ec];                   // unconditional load
                uint4 u  = *(const uint4*)(t + (size_t)sj * 64 + fo);
                float m  = (ej < end) ? 1.0f : 0.0f;
                float2 f0 = __half22float2(*(const __half2*)&u.x);
                float2 f1 = __half22float2(*(const __half2*)&u.y);
                float2 f2 = __half22float2(*(const __half2*)&u.z);
                float2 f3 = __half22float2(*(const __half2*)&u.w);
                if (j & 1) {
                    aB0.x = fmaf(m, f0.x, aB0.x);
                    aB0.y = fmaf(m, f0.y, aB0.y);
                    aB0.z = fmaf(m, f1.x, aB0.z);
                    aB0.w = fmaf(m, f1.y, aB0.w);
                    aB1.x = fmaf(m, f2.x, aB1.x);
                    aB1.y = fmaf(m, f2.y, aB1.y);
                    aB1.z = fmaf(m, f3.x, aB1.z);
                    aB1.w = fmaf(m, f3.y, aB1.w);
                } else {
                    aA0.x = fmaf(m, f0.x, aA0.x);
                    aA0.y = fmaf(m, f0.y, aA0.y);
                    aA0.z = fmaf(m, f1.x, aA0.z);
                    aA0.w = fmaf(m, f1.y, aA0.w);
                    aA1.x = fmaf(m, f2.x, aA1.x);
                    aA1.y = fmaf(m, f2.y, aA1.y);
                    aA1.z = fmaf(m, f3.x, aA1.z);
                    aA1.w = fmaf(m, f3.y, aA1.w);
                }
            }
        }
        s0 = __half22float2(*(const __half2*)&su.x);
        s1 = __half22float2(*(const __half2*)&su.y);
        s2 = __half22float2(*(const __half2*)&su.z);
        s3 = __half22float2(*(const __half2*)&su.w);
    }
    // combine even/odd ILP sets, then merge sub-halves (lane^8 same group)
    float4 c0, c1;
    c0.x = aA0.x + aB0.x; c0.y = aA0.y + aB0.y;
    c0.z = aA0.z + aB0.z; c0.w = aA0.w + aB0.w;
    c1.x = aA1.x + aB1.x; c1.y = aA1.y + aB1.y;
    c1.z = aA1.z + aB1.z; c1.w = aA1.w + aB1.w;
    c0.x += __shfl_xor(c0.x, 8, 64);
    c0.y += __shfl_xor(c0.y, 8, 64);
    c0.z += __shfl_xor(c0.z, 8, 64);
    c0.w += __shfl_xor(c0.w, 8, 64);
    c1.x += __shfl_xor(c1.x, 8, 64);
    c1.y += __shfl_xor(c1.y, 8, 64);
    c1.z += __shfl_xor(c1.z, 8, 64);
    c1.w += __shfl_xor(c1.w, 8, 64);

    if (i < n) {
        float4 bv0 = *(const float4*)(bias + fo);
        float4 bv1 = *(const float4*)(bias + fo + 4);
        float4 h4a, h4b;
        h4a.x = fmaxf(fmaf(dv, c0.x + s0.x, bv0.x), 0.0f);
        h4a.y = fmaxf(fmaf(dv, c0.y + s0.y, bv0.y), 0.0f);
        h4a.z = fmaxf(fmaf(dv, c0.z + s1.x, bv0.z), 0.0f);
        h4a.w = fmaxf(fmaf(dv, c0.w + s1.y, bv0.w), 0.0f);
        h4b.x = fmaxf(fmaf(dv, c1.x + s2.x, bv1.x), 0.0f);
        h4b.y = fmaxf(fmaf(dv, c1.y + s2.y, bv1.y), 0.0f);
        h4b.z = fmaxf(fmaf(dv, c1.z + s3.x, bv1.z), 0.0f);
        h4b.w = fmaxf(fmaf(dv, c1.w + s3.y, bv1.w), 0.0f);
        *(float4*)(hs + nl * 64 + fo)     = h4a;
        *(float4*)(hs + nl * 64 + fo + 4) = h4b;
        if ((lane & 15) == 0) dvs[nl] = dv;
    }
    // NO __syncthreads(): rows 4w..4w+3 / dvs[4w..4w+3] wave-private (R27).

    // ---- mm phase (4 rows/wave, W amortized) ----
    float4 wreg[16];
    const float4* W4 = (const float4*)(W + lane * 64);
#pragma unroll
    for (int q = 0; q < 16; ++q) wreg[q] = W4[q];
#pragma unroll
    for (int rr = 0; rr < 4; ++rr) {
        int r  = wave * 4 + rr;
        int io = base + r;
        if (io < n) {
            const float4* row = (const float4*)(hs + r * 64);
            float acc = 0.0f;
#pragma unroll
            for (int q = 0; q < 16; ++q) {
                float4 hv = row[q];  // wave-uniform address -> LDS broadcast
                acc += hv.x * wreg[q].x + hv.y * wreg[q].y +
                       hv.z * wreg[q].z + hv.w * wreg[q].w;
            }
            tout[(size_t)io * 64 + lane] = __float2half(acc * dvs[r]);
        }
    }
}

// Final layer (R29, kept): 4-group slice gather, 16B/lane, 8-edge rounds
// (j<4: 2 edges/instr, 4 load-instrs/round). Merge sub (xor8) + groups
// (xor16/32) -> h3 (8 features/lane, all lanes) -> z = h3 . Wl^T:
// slot=lane>>3 computes outputs slot & slot+8, xor-reduce 1,2,4 over chunks,
// (lane&7)==0 lanes do 16 atomicAdds of z*inv_cnt into bl-seeded out.
__global__ __launch_bounds__(256, 6) void aggfinal_kernel(const __half* __restrict__ t,
                                                          const int* __restrict__ rp,
                                                          const int* __restrict__ cs,
                                                          const float* __restrict__ dinv,
                                                          const float* __restrict__ bias,
                                                          const float* __restrict__ Wl,
                                                          const int* __restrict__ batch,
                                                          const float* __restrict__ invc,
                                                          float* __restrict__ out, int n) {
    int gw   = (blockIdx.x * blockDim.x + threadIdx.x) >> 6;
    int lane = threadIdx.x & 63;
    if (gw >= n) return;
    int i   = gw;
    int grp = lane >> 4;
    int sub = (lane >> 3) & 1;
    int fo  = (lane & 7) << 3;  // 8 features per lane
    int beg = rp[i];
    int end = rp[i + 1];
    uint4 su = *(const uint4*)(t + (size_t)i * 64 + fo);
    float dv = dinv[i];

    int deg = end - beg;
    int len = (deg + 3) >> 2;
    int gb  = beg + grp * len;
    int ge  = min(gb + len, end);

    float4 aA0 = make_float4(0.f, 0.f, 0.f, 0.f);
    float4 aA1 = aA0, aB0 = aA0, aB1 = aA0;
    for (int eb = gb; eb < ge; eb += 8) {
#pragma unroll
        for (int j = 0; j < 4; ++j) {
            int   ej = eb + 2 * j + sub;       // covers eb..eb+7 across sub
            int   ec = min(ej, end - 1);
            int   sj = cs[ec];
            uint4 u  = *(const uint4*)(t + (size_t)sj * 64 + fo);
            float m  = (ej < ge) ? 1.0f : 0.0f;
            float2 f0 = __half22float2(*(const __half2*)&u.x);
            float2 f1 = __half22float2(*(const __half2*)&u.y);
            float2 f2 = __half22float2(*(const __half2*)&u.z);
            float2 f3 = __half22float2(*(const __half2*)&u.w);
            if (j & 1) {
                aB0.x = fmaf(m, f0.x, aB0.x);
                aB0.y = fmaf(m, f0.y, aB0.y);
                aB0.z = fmaf(m, f1.x, aB0.z);
                aB0.w = fmaf(m, f1.y, aB0.w);
                aB1.x = fmaf(m, f2.x, aB1.x);
                aB1.y = fmaf(m, f2.y, aB1.y);
                aB1.z = fmaf(m, f3.x, aB1.z);
                aB1.w = fmaf(m, f3.y, aB1.w);
            } else {
                aA0.x = fmaf(m, f0.x, aA0.x);
                aA0.y = fmaf(m, f0.y, aA0.y);
                aA0.z = fmaf(m, f1.x, aA0.z);
                aA0.w = fmaf(m, f1.y, aA0.w);
                aA1.x = fmaf(m, f2.x, aA1.x);
                aA1.y = fmaf(m, f2.y, aA1.y);
                aA1.z = fmaf(m, f3.x, aA1.z);
                aA1.w = fmaf(m, f3.y, aA1.w);
            }
        }
    }
    float4 c0, c1;
    c0.x = aA0.x + aB0.x; c0.y = aA0.y + aB0.y;
    c0.z = aA0.z + aB0.z; c0.w = aA0.w + aB0.w;
    c1.x = aA1.x + aB1.x; c1.y = aA1.y + aB1.y;
    c1.z = aA1.z + aB1.z; c1.w = aA1.w + aB1.w;
    // merge sub-halves then group slices: all lanes -> full neighbor sum
#pragma unroll
    for (int s = 8; s <= 32; s <<= 1) {
        c0.x += __shfl_xor(c0.x, s, 64);
        c0.y += __shfl_xor(c0.y, s, 64);
        c0.z += __shfl_xor(c0.z, s, 64);
        c0.w += __shfl_xor(c0.w, s, 64);
        c1.x += __shfl_xor(c1.x, s, 64);
        c1.y += __shfl_xor(c1.y, s, 64);
        c1.z += __shfl_xor(c1.z, s, 64);
        c1.w += __shfl_xor(c1.w, s, 64);
    }

    float2 s0 = __half22float2(*(const __half2*)&su.x);
    float2 s1 = __half22float2(*(const __half2*)&su.y);
    float2 s2 = __half22float2(*(const __half2*)&su.z);
    float2 s3 = __half22float2(*(const __half2*)&su.w);
    float4 bv0 = *(const float4*)(bias + fo);
    float4 bv1 = *(const float4*)(bias + fo + 4);
    float4 h4a, h4b;
    h4a.x = fmaxf(fmaf(dv, c0.x + s0.x, bv0.x), 0.0f);
    h4a.y = fmaxf(fmaf(dv, c0.y + s0.y, bv0.y), 0.0f);
    h4a.z = fmaxf(fmaf(dv, c0.z + s1.x, bv0.z), 0.0f);
    h4a.w = fmaxf(fmaf(dv, c0.w + s1.y, bv0.w), 0.0f);
    h4b.x = fmaxf(fmaf(dv, c1.x + s2.x, bv1.x), 0.0f);
    h4b.y = fmaxf(fmaf(dv, c1.y + s2.y, bv1.y), 0.0f);
    h4b.z = fmaxf(fmaf(dv, c1.z + s3.x, bv1.z), 0.0f);
    h4b.w = fmaxf(fmaf(dv, c1.w + s3.y, bv1.w), 0.0f);

    // z[o] = h3 . Wl[o]: slot = lane>>3 handles o = slot and slot+8 using
    // its own 8-feature chunk; xor 1,2,4 sums over the 8 chunks.
    int slot = lane >> 3;
    const float4* wlA = (const float4*)(Wl + slot * 64 + fo);
    const float4* wlB = (const float4*)(Wl + (slot + 8) * 64 + fo);
    float4 wa0 = wlA[0], wa1 = wlA[1];
    float4 wb0 = wlB[0], wb1 = wlB[1];
    float zA = h4a.x * wa0.x + h4a.y * wa0.y + h4a.z * wa0.z + h4a.w * wa0.w +
               h4b.x * wa1.x + h4b.y * wa1.y + h4b.z * wa1.z + h4b.w * wa1.w;
    float zB = h4a.x * wb0.x + h4a.y * wb0.y + h4a.z * wb0.z + h4a.w * wb0.w +
               h4b.x * wb1.x + h4b.y * wb1.y + h4b.z * wb1.z + h4b.w * wb1.w;
#pragma unroll
    for (int s = 1; s <= 4; s <<= 1) {
        zA += __shfl_xor(zA, s, 64);
        zB += __shfl_xor(zB, s, 64);
    }
    if ((lane & 7) == 0) {
        int   b  = batch[i];
        float ic = invc[b];
        atomicAdd(out + b * 16 + slot,     zA * ic);
        atomicAdd(out + b * 16 + slot + 8, zB * ic);
    }
}

extern "C" void kernel_launch(void* const* d_in, const int* in_sizes, int n_in,
                              void* d_out, int out_size, void* d_ws, size_t ws_size,
                              hipStream_t stream) {
    const float* x    = (const float*)d_in[0];
    const int*   ei   = (const int*)d_in[1];
    const int*   batch= (const int*)d_in[2];
    const float* W1   = (const float*)d_in[3];
    const float* b1   = (const float*)d_in[4];
    const float* W2   = (const float*)d_in[5];
    const float* b2   = (const float*)d_in[6];
    const float* W3   = (const float*)d_in[7];
    const float* b3   = (const float*)d_in[8];
    const float* Wl   = (const float*)d_in[9];
    const float* bl   = (const float*)d_in[10];
    float* out = (float*)d_out;

    int n  = in_sizes[0] / 64;   // 50000 nodes
    int e  = in_sizes[1] / 2;    // 1250000 edges
    int nb = out_size / 16;      // 512 graphs

    const int* esrc = ei;
    const int* edst = ei + e;

    char* p = (char*)d_ws;
    auto carve = [&](size_t bytes) {
        char* r = p;
        p += (bytes + 255) & ~(size_t)255;
        return r;
    };
    float*  dinv  = (float*)carve((size_t)n * 4);
    int*    rp    = (int*)  carve((size_t)(n + 1) * 4);
    int*    csr   = (int*)  carve((size_t)e * 4);
    __half* tA    = (__half*)carve((size_t)n * 64 * 2);  // t1 / t3
    __half* tB    = (__half*)carve((size_t)n * 64 * 2);  // t2
    int2*   recs2 = (int2*) carve((size_t)512 * CAPB * 8);
    int*    fctr  = (int*)  carve(512 * 4);
    float*  invc  = (float*)carve((size_t)nb * 4);

    dim3 blk(256);
    int gBIN = (e + BINTILE - 1) / BINTILE;  // 306 tiles
    int gFUS = (n + 15) / 16;                // 16 nodes / 256-thr block
    int gAGG = (n + 3) / 4;                  // one node per wave (aggfinal)

    init_kernel<<<2, blk, 0, stream>>>(fctr, batch, bl, invc, out, n, nb);
    bin512_kernel<<<gBIN, blk, 0, stream>>>(esrc, edst, fctr, recs2, e, n);
    sortfill_mm_kernel<<<512, blk, 0, stream>>>(recs2, fctr, rp, dinv, csr,
                                                x, W1, tA, n);
    aggmm_kernel<<<gFUS, blk, 0, stream>>>(tA, rp, csr, dinv, b1, W2, tB, n);
    aggmm_kernel<<<gFUS, blk, 0, stream>>>(tB, rp, csr, dinv, b2, W3, tA, n);
    aggfinal_kernel<<<gAGG, blk, 0, stream>>>(tA, rp, csr, dinv, b3, Wl,
                                              batch, invc, out, n);
}

// Round 12
// 272.853 us; speedup vs baseline: 1.3970x; 1.3970x over previous
//
#include <hip/hip_runtime.h>
#include <hip/hip_fp16.h>

// ---------------------------------------------------------------------------
// GCN (3 layers) + global mean pool + linear, fp32 in/out, MI355X.
// t'[i] = dinv[i] * h[i] W^T; h_next[i] = relu(dinv[i]*(t'[i]+sum t'[j]) + b)
// R9: fp16 t (128B row = 1 L2 line), absmax 1.2e-4.
// R20/R23/R24: compiler refuses >8-deep load windows (16 dest VGPRs max).
// R25: L2 half-tiling FAILED; gather NOT miss-bound.
// R26: barrier straggler coupling governs; occupancy anti-correlated.
// R27 (WIN): no-__syncthreads aggmm (wave-private LDS rows). 280.67.
// R28/R29 (WIN, 278.6): 16B/lane uint4 gather; aggmm 16-edge rounds,
//   aggfinal 8-edge rounds. aggmm 49.9us @ occupancy 29.6% (VGPR 56).
// R30 FAILED BY SPILL, NOT BY THEORY: launch_bounds(256,8) capped VGPR=32 <
//   wreg[16]'s 64 -> scratch spill (WRITE 6.25->128MB, FETCH 42->147MB,
//   105us). Occupancy DID jump to 62% -> retention mechanism real.
// R31 (this round): retention experiment with NON-BINDING bound:
//   launch_bounds(256,4) -> VGPR cap 128 (kernel needs ~56, no spill),
//   4 waves/block, 16 nodes, grid 3125. Verification bits: WRITE back to
//   6.25MB, VGPR ~56. If aggmm <48: retention win. If >=50: R29 is floor.
// ---------------------------------------------------------------------------

#define CAPB 3072
#define BINTILE 4096

// fctr zero + per-graph inverse counts (binary search on sorted batch) +
// out seeded with bl (aggfinal accumulates atomically on top).
__global__ __launch_bounds__(256) void init_kernel(int* __restrict__ fctr,
                                                   const int* __restrict__ batch,
                                                   const float* __restrict__ bl,
                                                   float* __restrict__ invc,
                                                   float* __restrict__ out,
                                                   int n, int nb) {
    int t = blockIdx.x * blockDim.x + threadIdx.x;
    if (t < 512) fctr[t] = 0;
    if (t < nb) {
        int l = 0, r = n;
        while (l < r) { int m = (l + r) >> 1; if (batch[m] < t) l = m + 1; else r = m; }
        int lo = l;
        r = n;
        while (l < r) { int m = (l + r) >> 1; if (batch[m] < t + 1) l = m + 1; else r = m; }
        invc[t] = 1.0f / fmaxf((float)(l - lo), 1.0f);
#pragma unroll
        for (int o = 0; o < 16; ++o) out[t * 16 + o] = bl[o];
    }
}

// Bucket edges into 512 fine dst-ranges (fixed capacity CAPB, base=g*CAPB).
__global__ __launch_bounds__(256) void bin512_kernel(const int* __restrict__ src,
                                                     const int* __restrict__ dst,
                                                     int* __restrict__ fctr,
                                                     int2* __restrict__ recs2,
                                                     int e, int n) {
    __shared__ int lcnt[512], gbase[512];
    int tid = threadIdx.x;
    int s0  = blockIdx.x * BINTILE;
    lcnt[tid] = 0;
    lcnt[tid + 256] = 0;
    __syncthreads();
    int dv[16], bk[16];
#pragma unroll
    for (int k = 0; k < 16; ++k) {
        int i = s0 + tid + k * 256;  // coalesced
        if (i < e) {
            dv[k] = dst[i];
            bk[k] = (int)((512LL * dv[k]) / n);
            atomicAdd(&lcnt[bk[k]], 1);
        } else {
            bk[k] = -1;
        }
    }
    __syncthreads();
#pragma unroll
    for (int j = 0; j < 2; ++j) {
        int b = tid + j * 256;
        gbase[b] = b * CAPB + atomicAdd(&fctr[b], lcnt[b]);
        lcnt[b]  = 0;  // reuse as placement counter
    }
    __syncthreads();
#pragma unroll
    for (int k = 0; k < 16; ++k) {
        if (bk[k] >= 0) {
            int i = s0 + tid + k * 256;
            int p = gbase[bk[k]] + atomicAdd(&lcnt[bk[k]], 1);
            if (p < (bk[k] + 1) * CAPB) recs2[p] = make_int2(src[i], dv[k]);
        }
    }
}

// One block per fine bucket: LDS counting sort -> dense csr, rp/dinv, then
// fused mm1 for this bucket's nodes: t1 = fp16(dinv * x W1^T).
__global__ __launch_bounds__(256) void sortfill_mm_kernel(
    const int2* __restrict__ recs2, const int* __restrict__ fctr,
    int* __restrict__ rp, float* __restrict__ dinv, int* __restrict__ csr,
    const float* __restrict__ x, const float* __restrict__ W1,
    __half* __restrict__ t1, int n) {
    __shared__ int hist[128];
    __shared__ int lofs[129];
    __shared__ int stage[CAPB];
    __shared__ int redbuf[256];
    __shared__ float xrow[98 * 64];  // 25KB
    int g   = blockIdx.x;
    int N0  = (int)(((long long)n * g + 511) / 512);
    int N1  = (int)(((long long)n * (g + 1) + 511) / 512);
    int nn  = N1 - N0;  // <= 98
    int tid = threadIdx.x;
    int lane = tid & 63;
    int wave = tid >> 6;

    int partial = 0;
    for (int j = tid; j < g; j += 256) partial += min(fctr[j], CAPB);
    redbuf[tid] = partial;
    if (tid < 128) hist[tid] = 0;
    __syncthreads();
    for (int s = 128; s > 0; s >>= 1) {
        if (tid < s) redbuf[tid] += redbuf[tid + s];
        __syncthreads();
    }
    int base = redbuf[0];
    const int2* my = recs2 + (size_t)g * CAPB;
    int total = min(fctr[g], CAPB);
    for (int i = tid; i < total; i += 256)
        atomicAdd(&hist[my[i].y - N0], 1);
    __syncthreads();
    if (tid == 0) {
        int acc = 0;
        for (int k = 0; k < nn; ++k) { lofs[k] = acc; acc += hist[k]; }
        lofs[nn] = acc;
    }
    __syncthreads();
    if (tid < 128) hist[tid] = 0;  // placement counters
    __syncthreads();
    for (int i = tid; i < total; i += 256) {
        int2 rec = my[i];
        int  li  = rec.y - N0;
        int  pos = lofs[li] + atomicAdd(&hist[li], 1);
        stage[pos] = rec.x;  // pos < total <= CAPB
    }
    __syncthreads();
    for (int j = tid; j < total; j += 256) csr[base + j] = stage[j];
    if (tid < nn) {
        rp[N0 + tid]   = base + lofs[tid];
        int deg        = lofs[tid + 1] - lofs[tid];
        dinv[N0 + tid] = rsqrtf((float)(deg + 1));
    }
    if (g == 511 && tid == 0) rp[n] = base + total;

    // ---- fused mm1 for this bucket's nodes ----
    for (int idx = tid; idx < nn * 16; idx += 256)
        ((float4*)xrow)[idx] = ((const float4*)(x + (size_t)N0 * 64))[idx];
    float4 wreg[16];
    const float4* W4 = (const float4*)(W1 + lane * 64);
#pragma unroll
    for (int q = 0; q < 16; ++q) wreg[q] = W4[q];
    __syncthreads();
    for (int li = wave; li < nn; li += 4) {
        float dv = rsqrtf((float)(lofs[li + 1] - lofs[li] + 1));
        const float4* row = (const float4*)(xrow + li * 64);
        float acc = 0.0f;
#pragma unroll
        for (int q = 0; q < 16; ++q) {
            float4 hv = row[q];  // wave-uniform -> LDS broadcast
            acc += hv.x * wreg[q].x + hv.y * wreg[q].y +
                   hv.z * wreg[q].z + hv.w * wreg[q].w;
        }
        t1[(size_t)(N0 + li) * 64 + lane] = __float2half(acc * dv);
    }
}

// Fused agg(layer k) + mm(layer k+1): 256 thr = 4 waves, 16 nodes/block
// (R31: retention granule max-of-4, NON-BINDING launch_bounds(256,4) ->
// VGPR cap 128, no spill). GATHER (R28): one node per 16-lane group,
// 16B/lane uint4, 2 edges per group-instr, 16-edge rounds. shfl_xor(8)
// merges even/odd partials. h rows -> LDS wave-private rows 4w..4w+3,
// NO __syncthreads (R27).
// MM: W row per lane in 16 float4 regs (amortized over 4 rows/wave).
__global__ __launch_bounds__(256, 4) void aggmm_kernel(const __half* __restrict__ t,
                                                       const int* __restrict__ rp,
                                                       const int* __restrict__ cs,
                                                       const float* __restrict__ dinv,
                                                       const float* __restrict__ bias,
                                                       const float* __restrict__ W,
                                                       __half* __restrict__ tout, int n) {
    __shared__ float hs[16 * 64];  // 4KB, rows 4w..4w+3 private to wave w
    __shared__ float dvs[16];
    int tid  = threadIdx.x;
    int lane = tid & 63;
    int wave = tid >> 6;        // 0..3
    int g    = lane >> 4;       // group = node slot 0..3
    int sub  = (lane >> 3) & 1; // edge-parity slot within group
    int fo   = (lane & 7) << 3; // lane owns features fo..fo+7
    int base = blockIdx.x * 16;
    int nl   = wave * 4 + g;    // local node 0..15
    int i    = base + nl;

    float4 aA0 = make_float4(0.f, 0.f, 0.f, 0.f);
    float4 aA1 = aA0, aB0 = aA0, aB1 = aA0;
    float2 s0 = make_float2(0.f, 0.f), s1 = s0, s2 = s0, s3 = s0;
    float  dv = 1.0f;

    if (i < n) {
        int beg = rp[i];
        int end = rp[i + 1];
        uint4 su = *(const uint4*)(t + (size_t)i * 64 + fo);  // self row (early)
        dv = dinv[i];
        for (int eb = beg; eb < end; eb += 16) {
#pragma unroll
            for (int j = 0; j < 8; ++j) {
                int   ej = eb + 2 * j + sub;
                int   ec = min(ej, end - 1);         // in-bounds (loop => end>beg)
                int   sj = cs[ec];                   // unconditional load
                uint4 u  = *(const uint4*)(t + (size_t)sj * 64 + fo);
                float m  = (ej < end) ? 1.0f : 0.0f;
                float2 f0 = __half22float2(*(const __half2*)&u.x);
                float2 f1 = __half22float2(*(const __half2*)&u.y);
                float2 f2 = __half22float2(*(const __half2*)&u.z);
                float2 f3 = __half22float2(*(const __half2*)&u.w);
                if (j & 1) {
                    aB0.x = fmaf(m, f0.x, aB0.x);
                    aB0.y = fmaf(m, f0.y, aB0.y);
                    aB0.z = fmaf(m, f1.x, aB0.z);
                    aB0.w = fmaf(m, f1.y, aB0.w);
                    aB1.x = fmaf(m, f2.x, aB1.x);
                    aB1.y = fmaf(m, f2.y, aB1.y);
                    aB1.z = fmaf(m, f3.x, aB1.z);
                    aB1.w = fmaf(m, f3.y, aB1.w);
                } else {
                    aA0.x = fmaf(m, f0.x, aA0.x);
                    aA0.y = fmaf(m, f0.y, aA0.y);
                    aA0.z = fmaf(m, f1.x, aA0.z);
                    aA0.w = fmaf(m, f1.y, aA0.w);
                    aA1.x = fmaf(m, f2.x, aA1.x);
                    aA1.y = fmaf(m, f2.y, aA1.y);
                    aA1.z = fmaf(m, f3.x, aA1.z);
                    aA1.w = fmaf(m, f3.y, aA1.w);
                }
            }
        }
        s0 = __half22float2(*(const __half2*)&su.x);
        s1 = __half22float2(*(const __half2*)&su.y);
        s2 = __half22float2(*(const __half2*)&su.z);
        s3 = __half22float2(*(const __half2*)&su.w);
    }
    // combine even/odd ILP sets, then merge sub-halves (lane^8 same group)
    float4 c0, c1;
    c0.x = aA0.x + aB0.x; c0.y = aA0.y + aB0.y;
    c0.z = aA0.z + aB0.z; c0.w = aA0.w + aB0.w;
    c1.x = aA1.x + aB1.x; c1.y = aA1.y + aB1.y;
    c1.z = aA1.z + aB1.z; c1.w = aA1.w + aB1.w;
    c0.x += __shfl_xor(c0.x, 8, 64);
    c0.y += __shfl_xor(c0.y, 8, 64);
    c0.z += __shfl_xor(c0.z, 8, 64);
    c0.w += __shfl_xor(c0.w, 8, 64);
    c1.x += __shfl_xor(c1.x, 8, 64);
    c1.y += __shfl_xor(c1.y, 8, 64);
    c1.z += __shfl_xor(c1.z, 8, 64);
    c1.w += __shfl_xor(c1.w, 8, 64);

    if (i < n) {
        float4 bv0 = *(const float4*)(bias + fo);
        float4 bv1 = *(const float4*)(bias + fo + 4);
        float4 h4a, h4b;
        h4a.x = fmaxf(fmaf(dv, c0.x + s0.x, bv0.x), 0.0f);
        h4a.y = fmaxf(fmaf(dv, c0.y + s0.y, bv0.y), 0.0f);
        h4a.z = fmaxf(fmaf(dv, c0.z + s1.x, bv0.z), 0.0f);
        h4a.w = fmaxf(fmaf(dv, c0.w + s1.y, bv0.w), 0.0f);
        h4b.x = fmaxf(fmaf(dv, c1.x + s2.x, bv1.x), 0.0f);
        h4b.y = fmaxf(fmaf(dv, c1.y + s2.y, bv1.y), 0.0f);
        h4b.z = fmaxf(fmaf(dv, c1.z + s3.x, bv1.z), 0.0f);
        h4b.w = fmaxf(fmaf(dv, c1.w + s3.y, bv1.w), 0.0f);
        *(float4*)(hs + nl * 64 + fo)     = h4a;
        *(float4*)(hs + nl * 64 + fo + 4) = h4b;
        if ((lane & 15) == 0) dvs[nl] = dv;
    }
    // NO __syncthreads(): rows 4w..4w+3 / dvs[4w..4w+3] wave-private (R27).

    // ---- mm phase (4 rows/wave, W amortized) ----
    float4 wreg[16];
    const float4* W4 = (const float4*)(W + lane * 64);
#pragma unroll
    for (int q = 0; q < 16; ++q) wreg[q] = W4[q];
#pragma unroll
    for (int rr = 0; rr < 4; ++rr) {
        int r  = wave * 4 + rr;
        int io = base + r;
        if (io < n) {
            const float4* row = (const float4*)(hs + r * 64);
            float acc = 0.0f;
#pragma unroll
            for (int q = 0; q < 16; ++q) {
                float4 hv = row[q];  // wave-uniform address -> LDS broadcast
                acc += hv.x * wreg[q].x + hv.y * wreg[q].y +
                       hv.z * wreg[q].z + hv.w * wreg[q].w;
            }
            tout[(size_t)io * 64 + lane] = __float2half(acc * dvs[r]);
        }
    }
}

// Final layer (R29, kept): 4-group slice gather, 16B/lane, 8-edge rounds
// (j<4: 2 edges/instr, 4 load-instrs/round). Merge sub (xor8) + groups
// (xor16/32) -> h3 (8 features/lane, all lanes) -> z = h3 . Wl^T:
// slot=lane>>3 computes outputs slot & slot+8, xor-reduce 1,2,4 over chunks,
// (lane&7)==0 lanes do 16 atomicAdds of z*inv_cnt into bl-seeded out.
__global__ __launch_bounds__(256, 6) void aggfinal_kernel(const __half* __restrict__ t,
                                                          const int* __restrict__ rp,
                                                          const int* __restrict__ cs,
                                                          const float* __restrict__ dinv,
                                                          const float* __restrict__ bias,
                                                          const float* __restrict__ Wl,
                                                          const int* __restrict__ batch,
                                                          const float* __restrict__ invc,
                                                          float* __restrict__ out, int n) {
    int gw   = (blockIdx.x * blockDim.x + threadIdx.x) >> 6;
    int lane = threadIdx.x & 63;
    if (gw >= n) return;
    int i   = gw;
    int grp = lane >> 4;
    int sub = (lane >> 3) & 1;
    int fo  = (lane & 7) << 3;  // 8 features per lane
    int beg = rp[i];
    int end = rp[i + 1];
    uint4 su = *(const uint4*)(t + (size_t)i * 64 + fo);
    float dv = dinv[i];

    int deg = end - beg;
    int len = (deg + 3) >> 2;
    int gb  = beg + grp * len;
    int ge  = min(gb + len, end);

    float4 aA0 = make_float4(0.f, 0.f, 0.f, 0.f);
    float4 aA1 = aA0, aB0 = aA0, aB1 = aA0;
    for (int eb = gb; eb < ge; eb += 8) {
#pragma unroll
        for (int j = 0; j < 4; ++j) {
            int   ej = eb + 2 * j + sub;       // covers eb..eb+7 across sub
            int   ec = min(ej, end - 1);
            int   sj = cs[ec];
            uint4 u  = *(const uint4*)(t + (size_t)sj * 64 + fo);
            float m  = (ej < ge) ? 1.0f : 0.0f;
            float2 f0 = __half22float2(*(const __half2*)&u.x);
            float2 f1 = __half22float2(*(const __half2*)&u.y);
            float2 f2 = __half22float2(*(const __half2*)&u.z);
            float2 f3 = __half22float2(*(const __half2*)&u.w);
            if (j & 1) {
                aB0.x = fmaf(m, f0.x, aB0.x);
                aB0.y = fmaf(m, f0.y, aB0.y);
                aB0.z = fmaf(m, f1.x, aB0.z);
                aB0.w = fmaf(m, f1.y, aB0.w);
                aB1.x = fmaf(m, f2.x, aB1.x);
                aB1.y = fmaf(m, f2.y, aB1.y);
                aB1.z = fmaf(m, f3.x, aB1.z);
                aB1.w = fmaf(m, f3.y, aB1.w);
            } else {
                aA0.x = fmaf(m, f0.x, aA0.x);
                aA0.y = fmaf(m, f0.y, aA0.y);
                aA0.z = fmaf(m, f1.x, aA0.z);
                aA0.w = fmaf(m, f1.y, aA0.w);
                aA1.x = fmaf(m, f2.x, aA1.x);
                aA1.y = fmaf(m, f2.y, aA1.y);
                aA1.z = fmaf(m, f3.x, aA1.z);
                aA1.w = fmaf(m, f3.y, aA1.w);
            }
        }
    }
    float4 c0, c1;
    c0.x = aA0.x + aB0.x; c0.y = aA0.y + aB0.y;
    c0.z = aA0.z + aB0.z; c0.w = aA0.w + aB0.w;
    c1.x = aA1.x + aB1.x; c1.y = aA1.y + aB1.y;
    c1.z = aA1.z + aB1.z; c1.w = aA1.w + aB1.w;
    // merge sub-halves then group slices: all lanes -> full neighbor sum
#pragma unroll
    for (int s = 8; s <= 32; s <<= 1) {
        c0.x += __shfl_xor(c0.x, s, 64);
        c0.y += __shfl_xor(c0.y, s, 64);
        c0.z += __shfl_xor(c0.z, s, 64);
        c0.w += __shfl_xor(c0.w, s, 64);
        c1.x += __shfl_xor(c1.x, s, 64);
        c1.y += __shfl_xor(c1.y, s, 64);
        c1.z += __shfl_xor(c1.z, s, 64);
        c1.w += __shfl_xor(c1.w, s, 64);
    }

    float2 s0 = __half22float2(*(const __half2*)&su.x);
    float2 s1 = __half22float2(*(const __half2*)&su.y);
    float2 s2 = __half22float2(*(const __half2*)&su.z);
    float2 s3 = __half22float2(*(const __half2*)&su.w);
    float4 bv0 = *(const float4*)(bias + fo);
    float4 bv1 = *(const float4*)(bias + fo + 4);
    float4 h4a, h4b;
    h4a.x = fmaxf(fmaf(dv, c0.x + s0.x, bv0.x), 0.0f);
    h4a.y = fmaxf(fmaf(dv, c0.y + s0.y, bv0.y), 0.0f);
    h4a.z = fmaxf(fmaf(dv, c0.z + s1.x, bv0.z), 0.0f);
    h4a.w = fmaxf(fmaf(dv, c0.w + s1.y, bv0.w), 0.0f);
    h4b.x = fmaxf(fmaf(dv, c1.x + s2.x, bv1.x), 0.0f);
    h4b.y = fmaxf(fmaf(dv, c1.y + s2.y, bv1.y), 0.0f);
    h4b.z = fmaxf(fmaf(dv, c1.z + s3.x, bv1.z), 0.0f);
    h4b.w = fmaxf(fmaf(dv, c1.w + s3.y, bv1.w), 0.0f);

    // z[o] = h3 . Wl[o]: slot = lane>>3 handles o = slot and slot+8 using
    // its own 8-feature chunk; xor 1,2,4 sums over the 8 chunks.
    int slot = lane >> 3;
    const float4* wlA = (const float4*)(Wl + slot * 64 + fo);
    const float4* wlB = (const float4*)(Wl + (slot + 8) * 64 + fo);
    float4 wa0 = wlA[0], wa1 = wlA[1];
    float4 wb0 = wlB[0], wb1 = wlB[1];
    float zA = h4a.x * wa0.x + h4a.y * wa0.y + h4a.z * wa0.z + h4a.w * wa0.w +
               h4b.x * wa1.x + h4b.y * wa1.y + h4b.z * wa1.z + h4b.w * wa1.w;
    float zB = h4a.x * wb0.x + h4a.y * wb0.y + h4a.z * wb0.z + h4a.w * wb0.w +
               h4b.x * wb1.x + h4b.y * wb1.y + h4b.z * wb1.z + h4b.w * wb1.w;
#pragma unroll
    for (int s = 1; s <= 4; s <<= 1) {
        zA += __shfl_xor(zA, s, 64);
        zB += __shfl_xor(zB, s, 64);
    }
    if ((lane & 7) == 0) {
        int   b  = batch[i];
        float ic = invc[b];
        atomicAdd(out + b * 16 + slot,     zA * ic);
        atomicAdd(out + b * 16 + slot + 8, zB * ic);
    }
}

extern "C" void kernel_launch(void* const* d_in, const int* in_sizes, int n_in,
                              void* d_out, int out_size, void* d_ws, size_t ws_size,
                              hipStream_t stream) {
    const float* x    = (const float*)d_in[0];
    const int*   ei   = (const int*)d_in[1];
    const int*   batch= (const int*)d_in[2];
    const float* W1   = (const float*)d_in[3];
    const float* b1   = (const float*)d_in[4];
    const float* W2   = (const float*)d_in[5];
    const float* b2   = (const float*)d_in[6];
    const float* W3   = (const float*)d_in[7];
    const float* b3   = (const float*)d_in[8];
    const float* Wl   = (const float*)d_in[9];
    const float* bl   = (const float*)d_in[10];
    float* out = (float*)d_out;

    int n  = in_sizes[0] / 64;   // 50000 nodes
    int e  = in_sizes[1] / 2;    // 1250000 edges
    int nb = out_size / 16;      // 512 graphs

    const int* esrc = ei;
    const int* edst = ei + e;

    char* p = (char*)d_ws;
    auto carve = [&](size_t bytes) {
        char* r = p;
        p += (bytes + 255) & ~(size_t)255;
        return r;
    };
    float*  dinv  = (float*)carve((size_t)n * 4);
    int*    rp    = (int*)  carve((size_t)(n + 1) * 4);
    int*    csr   = (int*)  carve((size_t)e * 4);
    __half* tA    = (__half*)carve((size_t)n * 64 * 2);  // t1 / t3
    __half* tB    = (__half*)carve((size_t)n * 64 * 2);  // t2
    int2*   recs2 = (int2*) carve((size_t)512 * CAPB * 8);
    int*    fctr  = (int*)  carve(512 * 4);
    float*  invc  = (float*)carve((size_t)nb * 4);

    dim3 blk(256);
    int gBIN = (e + BINTILE - 1) / BINTILE;  // 306 tiles
    int gFUS = (n + 15) / 16;                // 16 nodes / 256-thr block
    int gAGG = (n + 3) / 4;                  // one node per wave (aggfinal)

    init_kernel<<<2, blk, 0, stream>>>(fctr, batch, bl, invc, out, n, nb);
    bin512_kernel<<<gBIN, blk, 0, stream>>>(esrc, edst, fctr, recs2, e, n);
    sortfill_mm_kernel<<<512, blk, 0, stream>>>(recs2, fctr, rp, dinv, csr,
                                                x, W1, tA, n);
    aggmm_kernel<<<gFUS, blk, 0, stream>>>(tA, rp, csr, dinv, b1, W2, tB, n);
    aggmm_kernel<<<gFUS, blk, 0, stream>>>(tB, rp, csr, dinv, b2, W3, tA, n);
    aggfinal_kernel<<<gAGG, blk, 0, stream>>>(tA, rp, csr, dinv, b3, Wl,
                                              batch, invc, out, n);
}

// Round 13
// 267.478 us; speedup vs baseline: 1.4251x; 1.0201x over previous
//
#include <hip/hip_runtime.h>
#include <hip/hip_fp16.h>

// ---------------------------------------------------------------------------
// GCN (3 layers) + global mean pool + linear, fp32 in/out, MI355X.
// t'[i] = dinv[i] * h[i] W^T; h_next[i] = relu(dinv[i]*(t'[i]+sum t'[j]) + b)
// R9: fp16 t (128B row = 1 L2 line), absmax 1.2e-4.
// R20/R23/R24: compiler refuses >8-deep load windows (16 dest VGPRs max).
// R25: L2 half-tiling FAILED; gather NOT miss-bound.
// R26: barrier straggler coupling governs; occupancy anti-correlated.
// R27 (WIN): no-__syncthreads aggmm (wave-private LDS rows). 280.67.
// R28/R29 (WIN, 278.6): 16B/lane uint4 gather (aggmm 16-edge rounds,
//   aggfinal 8-edge rounds).
// R30: binding launch_bounds(256,8) -> VGPR 32 -> SPILL (105us). Lesson:
//   check register budget before setting occupancy bounds.
// R31 (WIN, 272.9): retention granule max-of-4 w/ non-binding (256,4):
//   aggmm 49.9->46.5, VGPR 56, WRITE 6.25MB. Mechanism triple-confirmed:
//   zero-barrier blocks retain resources until slowest wave retires.
// R32 (this round): granule max-of-2 -- 128-thr blocks on BOTH gather
//   kernels. aggmm: 8 nodes/block, grid 6250, LDS 2KB; aggfinal: 2
//   nodes/block, grid 25000. Per-wave code identical (4 nodes/wave in
//   aggmm keeps W amortized -- R26 trap avoided). blocks/CU cap (>=16) x2
//   waves = 32 waves/CU ceiling, non-binding. launch_bounds(128,4) ->
//   VGPR cap 128 (R30 lesson). Pre-commit: <3us gain => roofline.
// ---------------------------------------------------------------------------

#define CAPB 3072
#define BINTILE 4096

// fctr zero + per-graph inverse counts (binary search on sorted batch) +
// out seeded with bl (aggfinal accumulates atomically on top).
__global__ __launch_bounds__(256) void init_kernel(int* __restrict__ fctr,
                                                   const int* __restrict__ batch,
                                                   const float* __restrict__ bl,
                                                   float* __restrict__ invc,
                                                   float* __restrict__ out,
                                                   int n, int nb) {
    int t = blockIdx.x * blockDim.x + threadIdx.x;
    if (t < 512) fctr[t] = 0;
    if (t < nb) {
        int l = 0, r = n;
        while (l < r) { int m = (l + r) >> 1; if (batch[m] < t) l = m + 1; else r = m; }
        int lo = l;
        r = n;
        while (l < r) { int m = (l + r) >> 1; if (batch[m] < t + 1) l = m + 1; else r = m; }
        invc[t] = 1.0f / fmaxf((float)(l - lo), 1.0f);
#pragma unroll
        for (int o = 0; o < 16; ++o) out[t * 16 + o] = bl[o];
    }
}

// Bucket edges into 512 fine dst-ranges (fixed capacity CAPB, base=g*CAPB).
__global__ __launch_bounds__(256) void bin512_kernel(const int* __restrict__ src,
                                                     const int* __restrict__ dst,
                                                     int* __restrict__ fctr,
                                                     int2* __restrict__ recs2,
                                                     int e, int n) {
    __shared__ int lcnt[512], gbase[512];
    int tid = threadIdx.x;
    int s0  = blockIdx.x * BINTILE;
    lcnt[tid] = 0;
    lcnt[tid + 256] = 0;
    __syncthreads();
    int dv[16], bk[16];
#pragma unroll
    for (int k = 0; k < 16; ++k) {
        int i = s0 + tid + k * 256;  // coalesced
        if (i < e) {
            dv[k] = dst[i];
            bk[k] = (int)((512LL * dv[k]) / n);
            atomicAdd(&lcnt[bk[k]], 1);
        } else {
            bk[k] = -1;
        }
    }
    __syncthreads();
#pragma unroll
    for (int j = 0; j < 2; ++j) {
        int b = tid + j * 256;
        gbase[b] = b * CAPB + atomicAdd(&fctr[b], lcnt[b]);
        lcnt[b]  = 0;  // reuse as placement counter
    }
    __syncthreads();
#pragma unroll
    for (int k = 0; k < 16; ++k) {
        if (bk[k] >= 0) {
            int i = s0 + tid + k * 256;
            int p = gbase[bk[k]] + atomicAdd(&lcnt[bk[k]], 1);
            if (p < (bk[k] + 1) * CAPB) recs2[p] = make_int2(src[i], dv[k]);
        }
    }
}

// One block per fine bucket: LDS counting sort -> dense csr, rp/dinv, then
// fused mm1 for this bucket's nodes: t1 = fp16(dinv * x W1^T).
__global__ __launch_bounds__(256) void sortfill_mm_kernel(
    const int2* __restrict__ recs2, const int* __restrict__ fctr,
    int* __restrict__ rp, float* __restrict__ dinv, int* __restrict__ csr,
    const float* __restrict__ x, const float* __restrict__ W1,
    __half* __restrict__ t1, int n) {
    __shared__ int hist[128];
    __shared__ int lofs[129];
    __shared__ int stage[CAPB];
    __shared__ int redbuf[256];
    __shared__ float xrow[98 * 64];  // 25KB
    int g   = blockIdx.x;
    int N0  = (int)(((long long)n * g + 511) / 512);
    int N1  = (int)(((long long)n * (g + 1) + 511) / 512);
    int nn  = N1 - N0;  // <= 98
    int tid = threadIdx.x;
    int lane = tid & 63;
    int wave = tid >> 6;

    int partial = 0;
    for (int j = tid; j < g; j += 256) partial += min(fctr[j], CAPB);
    redbuf[tid] = partial;
    if (tid < 128) hist[tid] = 0;
    __syncthreads();
    for (int s = 128; s > 0; s >>= 1) {
        if (tid < s) redbuf[tid] += redbuf[tid + s];
        __syncthreads();
    }
    int base = redbuf[0];
    const int2* my = recs2 + (size_t)g * CAPB;
    int total = min(fctr[g], CAPB);
    for (int i = tid; i < total; i += 256)
        atomicAdd(&hist[my[i].y - N0], 1);
    __syncthreads();
    if (tid == 0) {
        int acc = 0;
        for (int k = 0; k < nn; ++k) { lofs[k] = acc; acc += hist[k]; }
        lofs[nn] = acc;
    }
    __syncthreads();
    if (tid < 128) hist[tid] = 0;  // placement counters
    __syncthreads();
    for (int i = tid; i < total; i += 256) {
        int2 rec = my[i];
        int  li  = rec.y - N0;
        int  pos = lofs[li] + atomicAdd(&hist[li], 1);
        stage[pos] = rec.x;  // pos < total <= CAPB
    }
    __syncthreads();
    for (int j = tid; j < total; j += 256) csr[base + j] = stage[j];
    if (tid < nn) {
        rp[N0 + tid]   = base + lofs[tid];
        int deg        = lofs[tid + 1] - lofs[tid];
        dinv[N0 + tid] = rsqrtf((float)(deg + 1));
    }
    if (g == 511 && tid == 0) rp[n] = base + total;

    // ---- fused mm1 for this bucket's nodes ----
    for (int idx = tid; idx < nn * 16; idx += 256)
        ((float4*)xrow)[idx] = ((const float4*)(x + (size_t)N0 * 64))[idx];
    float4 wreg[16];
    const float4* W4 = (const float4*)(W1 + lane * 64);
#pragma unroll
    for (int q = 0; q < 16; ++q) wreg[q] = W4[q];
    __syncthreads();
    for (int li = wave; li < nn; li += 4) {
        float dv = rsqrtf((float)(lofs[li + 1] - lofs[li] + 1));
        const float4* row = (const float4*)(xrow + li * 64);
        float acc = 0.0f;
#pragma unroll
        for (int q = 0; q < 16; ++q) {
            float4 hv = row[q];  // wave-uniform -> LDS broadcast
            acc += hv.x * wreg[q].x + hv.y * wreg[q].y +
                   hv.z * wreg[q].z + hv.w * wreg[q].w;
        }
        t1[(size_t)(N0 + li) * 64 + lane] = __float2half(acc * dv);
    }
}

// Fused agg(layer k) + mm(layer k+1): 128 thr = 2 waves, 8 nodes/block
// (R32: retention granule max-of-2). GATHER (R28): one node per 16-lane
// group, 16B/lane uint4, 2 edges per group-instr, 16-edge rounds.
// shfl_xor(8) merges even/odd partials. h rows -> LDS wave-private rows
// 4w..4w+3, NO __syncthreads (R27).
// MM: W row per lane in 16 float4 regs (amortized over 4 rows/wave).
__global__ __launch_bounds__(128, 4) void aggmm_kernel(const __half* __restrict__ t,
                                                       const int* __restrict__ rp,
                                                       const int* __restrict__ cs,
                                                       const float* __restrict__ dinv,
                                                       const float* __restrict__ bias,
                                                       const float* __restrict__ W,
                                                       __half* __restrict__ tout, int n) {
    __shared__ float hs[8 * 64];  // 2KB, rows 4w..4w+3 private to wave w
    __shared__ float dvs[8];
    int tid  = threadIdx.x;
    int lane = tid & 63;
    int wave = tid >> 6;        // 0..1
    int g    = lane >> 4;       // group = node slot 0..3
    int sub  = (lane >> 3) & 1; // edge-parity slot within group
    int fo   = (lane & 7) << 3; // lane owns features fo..fo+7
    int base = blockIdx.x * 8;
    int nl   = wave * 4 + g;    // local node 0..7
    int i    = base + nl;

    float4 aA0 = make_float4(0.f, 0.f, 0.f, 0.f);
    float4 aA1 = aA0, aB0 = aA0, aB1 = aA0;
    float2 s0 = make_float2(0.f, 0.f), s1 = s0, s2 = s0, s3 = s0;
    float  dv = 1.0f;

    if (i < n) {
        int beg = rp[i];
        int end = rp[i + 1];
        uint4 su = *(const uint4*)(t + (size_t)i * 64 + fo);  // self row (early)
        dv = dinv[i];
        for (int eb = beg; eb < end; eb += 16) {
#pragma unroll
            for (int j = 0; j < 8; ++j) {
                int   ej = eb + 2 * j + sub;
                int   ec = min(ej, end - 1);         // in-bounds (loop => end>beg)
                int   sj = cs[ec];                   // unconditional load
                uint4 u  = *(const uint4*)(t + (size_t)sj * 64 + fo);
                float m  = (ej < end) ? 1.0f : 0.0f;
                float2 f0 = __half22float2(*(const __half2*)&u.x);
                float2 f1 = __half22float2(*(const __half2*)&u.y);
                float2 f2 = __half22float2(*(const __half2*)&u.z);
                float2 f3 = __half22float2(*(const __half2*)&u.w);
                if (j & 1) {
                    aB0.x = fmaf(m, f0.x, aB0.x);
                    aB0.y = fmaf(m, f0.y, aB0.y);
                    aB0.z = fmaf(m, f1.x, aB0.z);
                    aB0.w = fmaf(m, f1.y, aB0.w);
                    aB1.x = fmaf(m, f2.x, aB1.x);
                    aB1.y = fmaf(m, f2.y, aB1.y);
                    aB1.z = fmaf(m, f3.x, aB1.z);
                    aB1.w = fmaf(m, f3.y, aB1.w);
                } else {
                    aA0.x = fmaf(m, f0.x, aA0.x);
                    aA0.y = fmaf(m, f0.y, aA0.y);
                    aA0.z = fmaf(m, f1.x, aA0.z);
                    aA0.w = fmaf(m, f1.y, aA0.w);
                    aA1.x = fmaf(m, f2.x, aA1.x);
                    aA1.y = fmaf(m, f2.y, aA1.y);
                    aA1.z = fmaf(m, f3.x, aA1.z);
                    aA1.w = fmaf(m, f3.y, aA1.w);
                }
            }
        }
        s0 = __half22float2(*(const __half2*)&su.x);
        s1 = __half22float2(*(const __half2*)&su.y);
        s2 = __half22float2(*(const __half2*)&su.z);
        s3 = __half22float2(*(const __half2*)&su.w);
    }
    // combine even/odd ILP sets, then merge sub-halves (lane^8 same group)
    float4 c0, c1;
    c0.x = aA0.x + aB0.x; c0.y = aA0.y + aB0.y;
    c0.z = aA0.z + aB0.z; c0.w = aA0.w + aB0.w;
    c1.x = aA1.x + aB1.x; c1.y = aA1.y + aB1.y;
    c1.z = aA1.z + aB1.z; c1.w = aA1.w + aB1.w;
    c0.x += __shfl_xor(c0.x, 8, 64);
    c0.y += __shfl_xor(c0.y, 8, 64);
    c0.z += __shfl_xor(c0.z, 8, 64);
    c0.w += __shfl_xor(c0.w, 8, 64);
    c1.x += __shfl_xor(c1.x, 8, 64);
    c1.y += __shfl_xor(c1.y, 8, 64);
    c1.z += __shfl_xor(c1.z, 8, 64);
    c1.w += __shfl_xor(c1.w, 8, 64);

    if (i < n) {
        float4 bv0 = *(const float4*)(bias + fo);
        float4 bv1 = *(const float4*)(bias + fo + 4);
        float4 h4a, h4b;
        h4a.x = fmaxf(fmaf(dv, c0.x + s0.x, bv0.x), 0.0f);
        h4a.y = fmaxf(fmaf(dv, c0.y + s0.y, bv0.y), 0.0f);
        h4a.z = fmaxf(fmaf(dv, c0.z + s1.x, bv0.z), 0.0f);
        h4a.w = fmaxf(fmaf(dv, c0.w + s1.y, bv0.w), 0.0f);
        h4b.x = fmaxf(fmaf(dv, c1.x + s2.x, bv1.x), 0.0f);
        h4b.y = fmaxf(fmaf(dv, c1.y + s2.y, bv1.y), 0.0f);
        h4b.z = fmaxf(fmaf(dv, c1.z + s3.x, bv1.z), 0.0f);
        h4b.w = fmaxf(fmaf(dv, c1.w + s3.y, bv1.w), 0.0f);
        *(float4*)(hs + nl * 64 + fo)     = h4a;
        *(float4*)(hs + nl * 64 + fo + 4) = h4b;
        if ((lane & 15) == 0) dvs[nl] = dv;
    }
    // NO __syncthreads(): rows 4w..4w+3 / dvs[4w..4w+3] wave-private (R27).

    // ---- mm phase (4 rows/wave, W amortized) ----
    float4 wreg[16];
    const float4* W4 = (const float4*)(W + lane * 64);
#pragma unroll
    for (int q = 0; q < 16; ++q) wreg[q] = W4[q];
#pragma unroll
    for (int rr = 0; rr < 4; ++rr) {
        int r  = wave * 4 + rr;
        int io = base + r;
        if (io < n) {
            const float4* row = (const float4*)(hs + r * 64);
            float acc = 0.0f;
#pragma unroll
            for (int q = 0; q < 16; ++q) {
                float4 hv = row[q];  // wave-uniform address -> LDS broadcast
                acc += hv.x * wreg[q].x + hv.y * wreg[q].y +
                       hv.z * wreg[q].z + hv.w * wreg[q].w;
            }
            tout[(size_t)io * 64 + lane] = __float2half(acc * dvs[r]);
        }
    }
}

// Final layer (R29 body, R32 shape: 128 thr = 2 single-node waves/block,
// grid 25000, retention granule max-of-2): 4-group slice gather, 16B/lane,
// 8-edge rounds. Merge sub (xor8) + groups (xor16/32) -> h3 (8 features/
// lane, all lanes) -> z = h3 . Wl^T: slot=lane>>3 computes outputs slot &
// slot+8, xor-reduce 1,2,4 over chunks, (lane&7)==0 lanes do 16 atomicAdds
// of z*inv_cnt into bl-seeded out.
__global__ __launch_bounds__(128, 4) void aggfinal_kernel(const __half* __restrict__ t,
                                                          const int* __restrict__ rp,
                                                          const int* __restrict__ cs,
                                                          const float* __restrict__ dinv,
                                                          const float* __restrict__ bias,
                                                          const float* __restrict__ Wl,
                                                          const int* __restrict__ batch,
                                                          const float* __restrict__ invc,
                                                          float* __restrict__ out, int n) {
    int gw   = (blockIdx.x * blockDim.x + threadIdx.x) >> 6;
    int lane = threadIdx.x & 63;
    if (gw >= n) return;
    int i   = gw;
    int grp = lane >> 4;
    int sub = (lane >> 3) & 1;
    int fo  = (lane & 7) << 3;  // 8 features per lane
    int beg = rp[i];
    int end = rp[i + 1];
    uint4 su = *(const uint4*)(t + (size_t)i * 64 + fo);
    float dv = dinv[i];

    int deg = end - beg;
    int len = (deg + 3) >> 2;
    int gb  = beg + grp * len;
    int ge  = min(gb + len, end);

    float4 aA0 = make_float4(0.f, 0.f, 0.f, 0.f);
    float4 aA1 = aA0, aB0 = aA0, aB1 = aA0;
    for (int eb = gb; eb < ge; eb += 8) {
#pragma unroll
        for (int j = 0; j < 4; ++j) {
            int   ej = eb + 2 * j + sub;       // covers eb..eb+7 across sub
            int   ec = min(ej, end - 1);
            int   sj = cs[ec];
            uint4 u  = *(const uint4*)(t + (size_t)sj * 64 + fo);
            float m  = (ej < ge) ? 1.0f : 0.0f;
            float2 f0 = __half22float2(*(const __half2*)&u.x);
            float2 f1 = __half22float2(*(const __half2*)&u.y);
            float2 f2 = __half22float2(*(const __half2*)&u.z);
            float2 f3 = __half22float2(*(const __half2*)&u.w);
            if (j & 1) {
                aB0.x = fmaf(m, f0.x, aB0.x);
                aB0.y = fmaf(m, f0.y, aB0.y);
                aB0.z = fmaf(m, f1.x, aB0.z);
                aB0.w = fmaf(m, f1.y, aB0.w);
                aB1.x = fmaf(m, f2.x, aB1.x);
                aB1.y = fmaf(m, f2.y, aB1.y);
                aB1.z = fmaf(m, f3.x, aB1.z);
                aB1.w = fmaf(m, f3.y, aB1.w);
            } else {
                aA0.x = fmaf(m, f0.x, aA0.x);
                aA0.y = fmaf(m, f0.y, aA0.y);
                aA0.z = fmaf(m, f1.x, aA0.z);
                aA0.w = fmaf(m, f1.y, aA0.w);
                aA1.x = fmaf(m, f2.x, aA1.x);
                aA1.y = fmaf(m, f2.y, aA1.y);
                aA1.z = fmaf(m, f3.x, aA1.z);
                aA1.w = fmaf(m, f3.y, aA1.w);
            }
        }
    }
    float4 c0, c1;
    c0.x = aA0.x + aB0.x; c0.y = aA0.y + aB0.y;
    c0.z = aA0.z + aB0.z; c0.w = aA0.w + aB0.w;
    c1.x = aA1.x + aB1.x; c1.y = aA1.y + aB1.y;
    c1.z = aA1.z + aB1.z; c1.w = aA1.w + aB1.w;
    // merge sub-halves then group slices: all lanes -> full neighbor sum
#pragma unroll
    for (int s = 8; s <= 32; s <<= 1) {
        c0.x += __shfl_xor(c0.x, s, 64);
        c0.y += __shfl_xor(c0.y, s, 64);
        c0.z += __shfl_xor(c0.z, s, 64);
        c0.w += __shfl_xor(c0.w, s, 64);
        c1.x += __shfl_xor(c1.x, s, 64);
        c1.y += __shfl_xor(c1.y, s, 64);
        c1.z += __shfl_xor(c1.z, s, 64);
        c1.w += __shfl_xor(c1.w, s, 64);
    }

    float2 s0 = __half22float2(*(const __half2*)&su.x);
    float2 s1 = __half22float2(*(const __half2*)&su.y);
    float2 s2 = __half22float2(*(const __half2*)&su.z);
    float2 s3 = __half22float2(*(const __half2*)&su.w);
    float4 bv0 = *(const float4*)(bias + fo);
    float4 bv1 = *(const float4*)(bias + fo + 4);
    float4 h4a, h4b;
    h4a.x = fmaxf(fmaf(dv, c0.x + s0.x, bv0.x), 0.0f);
    h4a.y = fmaxf(fmaf(dv, c0.y + s0.y, bv0.y), 0.0f);
    h4a.z = fmaxf(fmaf(dv, c0.z + s1.x, bv0.z), 0.0f);
    h4a.w = fmaxf(fmaf(dv, c0.w + s1.y, bv0.w), 0.0f);
    h4b.x = fmaxf(fmaf(dv, c1.x + s2.x, bv1.x), 0.0f);
    h4b.y = fmaxf(fmaf(dv, c1.y + s2.y, bv1.y), 0.0f);
    h4b.z = fmaxf(fmaf(dv, c1.z + s3.x, bv1.z), 0.0f);
    h4b.w = fmaxf(fmaf(dv, c1.w + s3.y, bv1.w), 0.0f);

    // z[o] = h3 . Wl[o]: slot = lane>>3 handles o = slot and slot+8 using
    // its own 8-feature chunk; xor 1,2,4 sums over the 8 chunks.
    int slot = lane >> 3;
    const float4* wlA = (const float4*)(Wl + slot * 64 + fo);
    const float4* wlB = (const float4*)(Wl + (slot + 8) * 64 + fo);
    float4 wa0 = wlA[0], wa1 = wlA[1];
    float4 wb0 = wlB[0], wb1 = wlB[1];
    float zA = h4a.x * wa0.x + h4a.y * wa0.y + h4a.z * wa0.z + h4a.w * wa0.w +
               h4b.x * wa1.x + h4b.y * wa1.y + h4b.z * wa1.z + h4b.w * wa1.w;
    float zB = h4a.x * wb0.x + h4a.y * wb0.y + h4a.z * wb0.z + h4a.w * wb0.w +
               h4b.x * wb1.x + h4b.y * wb1.y + h4b.z * wb1.z + h4b.w * wb1.w;
#pragma unroll
    for (int s = 1; s <= 4; s <<= 1) {
        zA += __shfl_xor(zA, s, 64);
        zB += __shfl_xor(zB, s, 64);
    }
    if ((lane & 7) == 0) {
        int   b  = batch[i];
        float ic = invc[b];
        atomicAdd(out + b * 16 + slot,     zA * ic);
        atomicAdd(out + b * 16 + slot + 8, zB * ic);
    }
}

extern "C" void kernel_launch(void* const* d_in, const int* in_sizes, int n_in,
                              void* d_out, int out_size, void* d_ws, size_t ws_size,
                              hipStream_t stream) {
    const float* x    = (const float*)d_in[0];
    const int*   ei   = (const int*)d_in[1];
    const int*   batch= (const int*)d_in[2];
    const float* W1   = (const float*)d_in[3];
    const float* b1   = (const float*)d_in[4];
    const float* W2   = (const float*)d_in[5];
    const float* b2   = (const float*)d_in[6];
    const float* W3   = (const float*)d_in[7];
    const float* b3   = (const float*)d_in[8];
    const float* Wl   = (const float*)d_in[9];
    const float* bl   = (const float*)d_in[10];
    float* out = (float*)d_out;

    int n  = in_sizes[0] / 64;   // 50000 nodes
    int e  = in_sizes[1] / 2;    // 1250000 edges
    int nb = out_size / 16;      // 512 graphs

    const int* esrc = ei;
    const int* edst = ei + e;

    char* p = (char*)d_ws;
    auto carve = [&](size_t bytes) {
        char* r = p;
        p += (bytes + 255) & ~(size_t)255;
        return r;
    };
    float*  dinv  = (float*)carve((size_t)n * 4);
    int*    rp    = (int*)  carve((size_t)(n + 1) * 4);
    int*    csr   = (int*)  carve((size_t)e * 4);
    __half* tA    = (__half*)carve((size_t)n * 64 * 2);  // t1 / t3
    __half* tB    = (__half*)carve((size_t)n * 64 * 2);  // t2
    int2*   recs2 = (int2*) carve((size_t)512 * CAPB * 8);
    int*    fctr  = (int*)  carve(512 * 4);
    float*  invc  = (float*)carve((size_t)nb * 4);

    dim3 blk(256);
    dim3 blk128(128);
    int gBIN = (e + BINTILE - 1) / BINTILE;  // 306 tiles
    int gFUS = (n + 7) / 8;                  // 8 nodes / 128-thr block
    int gAGG = (n + 1) / 2;                  // 2 nodes / 128-thr block

    init_kernel<<<2, blk, 0, stream>>>(fctr, batch, bl, invc, out, n, nb);
    bin512_kernel<<<gBIN, blk, 0, stream>>>(esrc, edst, fctr, recs2, e, n);
    sortfill_mm_kernel<<<512, blk, 0, stream>>>(recs2, fctr, rp, dinv, csr,
                                                x, W1, tA, n);
    aggmm_kernel<<<gFUS, blk128, 0, stream>>>(tA, rp, csr, dinv, b1, W2, tB, n);
    aggmm_kernel<<<gFUS, blk128, 0, stream>>>(tB, rp, csr, dinv, b2, W3, tA, n);
    aggfinal_kernel<<<gAGG, blk128, 0, stream>>>(tA, rp, csr, dinv, b3, Wl,
                                                 batch, invc, out, n);
}

// Round 14
// 258.697 us; speedup vs baseline: 1.4735x; 1.0339x over previous
//
#include <hip/hip_runtime.h>
#include <hip/hip_fp16.h>

// ---------------------------------------------------------------------------
// GCN (3 layers) + global mean pool + linear, fp32 in/out, MI355X.
// t'[i] = dinv[i] * h[i] W^T; h_next[i] = relu(dinv[i]*(t'[i]+sum t'[j]) + b)
// R9: fp16 t (128B row = 1 L2 line), absmax 1.2e-4.
// R20/R23/R24: compiler refuses >8-deep load windows (16 dest VGPRs max).
// R25: L2 half-tiling FAILED; gather NOT miss-bound.
// R26: barrier straggler coupling governs; occupancy anti-correlated.
// R27 (WIN): no-__syncthreads aggmm (wave-private LDS rows). 280.67.
// R28/R29 (WIN, 278.6): 16B/lane uint4 gather (aggmm 16-edge rounds,
//   aggfinal 8-edge rounds).
// R30: binding launch_bounds(256,8) -> VGPR 32 -> SPILL. Check reg budget.
// R31 (WIN, 272.9): retention granule max-of-4 (256thr,4 waves): aggmm
//   49.9->46.5. Zero-barrier blocks retain resources until slowest wave.
// R32 (WIN, 267.5): granule max-of-2 (128thr): aggmm <45.5, aggfinal 45.6.
//   Curve: 8w->4w +6us, 4w->2w +5.4us. Still paying, flattening.
// R33 (this round): granule = 1 -- 64-thr single-wave blocks. Block retires
//   with its wave; zero straggler coupling. Caps don't bind: 32 blk/CU x 1
//   wave = 32 waves/CU ceiling; VGPR 56 allows 8/SIMD; LDS 1KB. aggmm: 4
//   nodes/block grid 12500 (wave owns 4 nodes -> W amortized, R26 trap
//   avoided); aggfinal: 1 node/block grid 50000. Pre-commit: <2us => done.
// ---------------------------------------------------------------------------

#define CAPB 3072
#define BINTILE 4096

// fctr zero + per-graph inverse counts (binary search on sorted batch) +
// out seeded with bl (aggfinal accumulates atomically on top).
__global__ __launch_bounds__(256) void init_kernel(int* __restrict__ fctr,
                                                   const int* __restrict__ batch,
                                                   const float* __restrict__ bl,
                                                   float* __restrict__ invc,
                                                   float* __restrict__ out,
                                                   int n, int nb) {
    int t = blockIdx.x * blockDim.x + threadIdx.x;
    if (t < 512) fctr[t] = 0;
    if (t < nb) {
        int l = 0, r = n;
        while (l < r) { int m = (l + r) >> 1; if (batch[m] < t) l = m + 1; else r = m; }
        int lo = l;
        r = n;
        while (l < r) { int m = (l + r) >> 1; if (batch[m] < t + 1) l = m + 1; else r = m; }
        invc[t] = 1.0f / fmaxf((float)(l - lo), 1.0f);
#pragma unroll
        for (int o = 0; o < 16; ++o) out[t * 16 + o] = bl[o];
    }
}

// Bucket edges into 512 fine dst-ranges (fixed capacity CAPB, base=g*CAPB).
__global__ __launch_bounds__(256) void bin512_kernel(const int* __restrict__ src,
                                                     const int* __restrict__ dst,
                                                     int* __restrict__ fctr,
                                                     int2* __restrict__ recs2,
                                                     int e, int n) {
    __shared__ int lcnt[512], gbase[512];
    int tid = threadIdx.x;
    int s0  = blockIdx.x * BINTILE;
    lcnt[tid] = 0;
    lcnt[tid + 256] = 0;
    __syncthreads();
    int dv[16], bk[16];
#pragma unroll
    for (int k = 0; k < 16; ++k) {
        int i = s0 + tid + k * 256;  // coalesced
        if (i < e) {
            dv[k] = dst[i];
            bk[k] = (int)((512LL * dv[k]) / n);
            atomicAdd(&lcnt[bk[k]], 1);
        } else {
            bk[k] = -1;
        }
    }
    __syncthreads();
#pragma unroll
    for (int j = 0; j < 2; ++j) {
        int b = tid + j * 256;
        gbase[b] = b * CAPB + atomicAdd(&fctr[b], lcnt[b]);
        lcnt[b]  = 0;  // reuse as placement counter
    }
    __syncthreads();
#pragma unroll
    for (int k = 0; k < 16; ++k) {
        if (bk[k] >= 0) {
            int i = s0 + tid + k * 256;
            int p = gbase[bk[k]] + atomicAdd(&lcnt[bk[k]], 1);
            if (p < (bk[k] + 1) * CAPB) recs2[p] = make_int2(src[i], dv[k]);
        }
    }
}

// One block per fine bucket: LDS counting sort -> dense csr, rp/dinv, then
// fused mm1 for this bucket's nodes: t1 = fp16(dinv * x W1^T).
__global__ __launch_bounds__(256) void sortfill_mm_kernel(
    const int2* __restrict__ recs2, const int* __restrict__ fctr,
    int* __restrict__ rp, float* __restrict__ dinv, int* __restrict__ csr,
    const float* __restrict__ x, const float* __restrict__ W1,
    __half* __restrict__ t1, int n) {
    __shared__ int hist[128];
    __shared__ int lofs[129];
    __shared__ int stage[CAPB];
    __shared__ int redbuf[256];
    __shared__ float xrow[98 * 64];  // 25KB
    int g   = blockIdx.x;
    int N0  = (int)(((long long)n * g + 511) / 512);
    int N1  = (int)(((long long)n * (g + 1) + 511) / 512);
    int nn  = N1 - N0;  // <= 98
    int tid = threadIdx.x;
    int lane = tid & 63;
    int wave = tid >> 6;

    int partial = 0;
    for (int j = tid; j < g; j += 256) partial += min(fctr[j], CAPB);
    redbuf[tid] = partial;
    if (tid < 128) hist[tid] = 0;
    __syncthreads();
    for (int s = 128; s > 0; s >>= 1) {
        if (tid < s) redbuf[tid] += redbuf[tid + s];
        __syncthreads();
    }
    int base = redbuf[0];
    const int2* my = recs2 + (size_t)g * CAPB;
    int total = min(fctr[g], CAPB);
    for (int i = tid; i < total; i += 256)
        atomicAdd(&hist[my[i].y - N0], 1);
    __syncthreads();
    if (tid == 0) {
        int acc = 0;
        for (int k = 0; k < nn; ++k) { lofs[k] = acc; acc += hist[k]; }
        lofs[nn] = acc;
    }
    __syncthreads();
    if (tid < 128) hist[tid] = 0;  // placement counters
    __syncthreads();
    for (int i = tid; i < total; i += 256) {
        int2 rec = my[i];
        int  li  = rec.y - N0;
        int  pos = lofs[li] + atomicAdd(&hist[li], 1);
        stage[pos] = rec.x;  // pos < total <= CAPB
    }
    __syncthreads();
    for (int j = tid; j < total; j += 256) csr[base + j] = stage[j];
    if (tid < nn) {
        rp[N0 + tid]   = base + lofs[tid];
        int deg        = lofs[tid + 1] - lofs[tid];
        dinv[N0 + tid] = rsqrtf((float)(deg + 1));
    }
    if (g == 511 && tid == 0) rp[n] = base + total;

    // ---- fused mm1 for this bucket's nodes ----
    for (int idx = tid; idx < nn * 16; idx += 256)
        ((float4*)xrow)[idx] = ((const float4*)(x + (size_t)N0 * 64))[idx];
    float4 wreg[16];
    const float4* W4 = (const float4*)(W1 + lane * 64);
#pragma unroll
    for (int q = 0; q < 16; ++q) wreg[q] = W4[q];
    __syncthreads();
    for (int li = wave; li < nn; li += 4) {
        float dv = rsqrtf((float)(lofs[li + 1] - lofs[li] + 1));
        const float4* row = (const float4*)(xrow + li * 64);
        float acc = 0.0f;
#pragma unroll
        for (int q = 0; q < 16; ++q) {
            float4 hv = row[q];  // wave-uniform -> LDS broadcast
            acc += hv.x * wreg[q].x + hv.y * wreg[q].y +
                   hv.z * wreg[q].z + hv.w * wreg[q].w;
        }
        t1[(size_t)(N0 + li) * 64 + lane] = __float2half(acc * dv);
    }
}

// Fused agg(layer k) + mm(layer k+1): 64 thr = ONE wave, 4 nodes/block
// (R33: retention granule = 1; block retires with its wave). GATHER (R28):
// one node per 16-lane group, 16B/lane uint4, 2 edges per group-instr,
// 16-edge rounds. shfl_xor(8) merges even/odd partials. h rows -> LDS
// (trivially wave-private, no barrier).
// MM: W row per lane in 16 float4 regs (amortized over 4 rows).
__global__ __launch_bounds__(64, 4) void aggmm_kernel(const __half* __restrict__ t,
                                                      const int* __restrict__ rp,
                                                      const int* __restrict__ cs,
                                                      const float* __restrict__ dinv,
                                                      const float* __restrict__ bias,
                                                      const float* __restrict__ W,
                                                      __half* __restrict__ tout, int n) {
    __shared__ float hs[4 * 64];  // 1KB
    __shared__ float dvs[4];
    int lane = threadIdx.x & 63;
    int g    = lane >> 4;       // group = node slot 0..3
    int sub  = (lane >> 3) & 1; // edge-parity slot within group
    int fo   = (lane & 7) << 3; // lane owns features fo..fo+7
    int base = blockIdx.x * 4;
    int i    = base + g;

    float4 aA0 = make_float4(0.f, 0.f, 0.f, 0.f);
    float4 aA1 = aA0, aB0 = aA0, aB1 = aA0;
    float2 s0 = make_float2(0.f, 0.f), s1 = s0, s2 = s0, s3 = s0;
    float  dv = 1.0f;

    if (i < n) {
        int beg = rp[i];
        int end = rp[i + 1];
        uint4 su = *(const uint4*)(t + (size_t)i * 64 + fo);  // self row (early)
        dv = dinv[i];
        for (int eb = beg; eb < end; eb += 16) {
#pragma unroll
            for (int j = 0; j < 8; ++j) {
                int   ej = eb + 2 * j + sub;
                int   ec = min(ej, end - 1);         // in-bounds (loop => end>beg)
                int   sj = cs[ec];                   // unconditional load
                uint4 u  = *(const uint4*)(t + (size_t)sj * 64 + fo);
                float m  = (ej < end) ? 1.0f : 0.0f;
                float2 f0 = __half22float2(*(const __half2*)&u.x);
                float2 f1 = __half22float2(*(const __half2*)&u.y);
                float2 f2 = __half22float2(*(const __half2*)&u.z);
                float2 f3 = __half22float2(*(const __half2*)&u.w);
                if (j & 1) {
                    aB0.x = fmaf(m, f0.x, aB0.x);
                    aB0.y = fmaf(m, f0.y, aB0.y);
                    aB0.z = fmaf(m, f1.x, aB0.z);
                    aB0.w = fmaf(m, f1.y, aB0.w);
                    aB1.x = fmaf(m, f2.x, aB1.x);
                    aB1.y = fmaf(m, f2.y, aB1.y);
                    aB1.z = fmaf(m, f3.x, aB1.z);
                    aB1.w = fmaf(m, f3.y, aB1.w);
                } else {
                    aA0.x = fmaf(m, f0.x, aA0.x);
                    aA0.y = fmaf(m, f0.y, aA0.y);
                    aA0.z = fmaf(m, f1.x, aA0.z);
                    aA0.w = fmaf(m, f1.y, aA0.w);
                    aA1.x = fmaf(m, f2.x, aA1.x);
                    aA1.y = fmaf(m, f2.y, aA1.y);
                    aA1.z = fmaf(m, f3.x, aA1.z);
                    aA1.w = fmaf(m, f3.y, aA1.w);
                }
            }
        }
        s0 = __half22float2(*(const __half2*)&su.x);
        s1 = __half22float2(*(const __half2*)&su.y);
        s2 = __half22float2(*(const __half2*)&su.z);
        s3 = __half22float2(*(const __half2*)&su.w);
    }
    // combine even/odd ILP sets, then merge sub-halves (lane^8 same group)
    float4 c0, c1;
    c0.x = aA0.x + aB0.x; c0.y = aA0.y + aB0.y;
    c0.z = aA0.z + aB0.z; c0.w = aA0.w + aB0.w;
    c1.x = aA1.x + aB1.x; c1.y = aA1.y + aB1.y;
    c1.z = aA1.z + aB1.z; c1.w = aA1.w + aB1.w;
    c0.x += __shfl_xor(c0.x, 8, 64);
    c0.y += __shfl_xor(c0.y, 8, 64);
    c0.z += __shfl_xor(c0.z, 8, 64);
    c0.w += __shfl_xor(c0.w, 8, 64);
    c1.x += __shfl_xor(c1.x, 8, 64);
    c1.y += __shfl_xor(c1.y, 8, 64);
    c1.z += __shfl_xor(c1.z, 8, 64);
    c1.w += __shfl_xor(c1.w, 8, 64);

    if (i < n) {
        float4 bv0 = *(const float4*)(bias + fo);
        float4 bv1 = *(const float4*)(bias + fo + 4);
        float4 h4a, h4b;
        h4a.x = fmaxf(fmaf(dv, c0.x + s0.x, bv0.x), 0.0f);
        h4a.y = fmaxf(fmaf(dv, c0.y + s0.y, bv0.y), 0.0f);
        h4a.z = fmaxf(fmaf(dv, c0.z + s1.x, bv0.z), 0.0f);
        h4a.w = fmaxf(fmaf(dv, c0.w + s1.y, bv0.w), 0.0f);
        h4b.x = fmaxf(fmaf(dv, c1.x + s2.x, bv1.x), 0.0f);
        h4b.y = fmaxf(fmaf(dv, c1.y + s2.y, bv1.y), 0.0f);
        h4b.z = fmaxf(fmaf(dv, c1.z + s3.x, bv1.z), 0.0f);
        h4b.w = fmaxf(fmaf(dv, c1.w + s3.y, bv1.w), 0.0f);
        *(float4*)(hs + g * 64 + fo)     = h4a;
        *(float4*)(hs + g * 64 + fo + 4) = h4b;
        if ((lane & 15) == 0) dvs[g] = dv;
    }
    // single-wave block: ds ordering intra-wave, no barrier needed.

    // ---- mm phase (4 rows, W amortized) ----
    float4 wreg[16];
    const float4* W4 = (const float4*)(W + lane * 64);
#pragma unroll
    for (int q = 0; q < 16; ++q) wreg[q] = W4[q];
#pragma unroll
    for (int rr = 0; rr < 4; ++rr) {
        int io = base + rr;
        if (io < n) {
            const float4* row = (const float4*)(hs + rr * 64);
            float acc = 0.0f;
#pragma unroll
            for (int q = 0; q < 16; ++q) {
                float4 hv = row[q];  // wave-uniform address -> LDS broadcast
                acc += hv.x * wreg[q].x + hv.y * wreg[q].y +
                       hv.z * wreg[q].z + hv.w * wreg[q].w;
            }
            tout[(size_t)io * 64 + lane] = __float2half(acc * dvs[rr]);
        }
    }
}

// Final layer (R29 body, R33 shape: 64 thr = 1 wave = 1 node/block, grid
// n, retention granule 1): 4-group slice gather, 16B/lane, 8-edge rounds.
// Merge sub (xor8) + groups (xor16/32) -> h3 (8 features/lane, all lanes)
// -> z = h3 . Wl^T: slot=lane>>3 computes outputs slot & slot+8, xor-reduce
// 1,2,4 over chunks, (lane&7)==0 lanes do 16 atomicAdds into bl-seeded out.
__global__ __launch_bounds__(64, 4) void aggfinal_kernel(const __half* __restrict__ t,
                                                         const int* __restrict__ rp,
                                                         const int* __restrict__ cs,
                                                         const float* __restrict__ dinv,
                                                         const float* __restrict__ bias,
                                                         const float* __restrict__ Wl,
                                                         const int* __restrict__ batch,
                                                         const float* __restrict__ invc,
                                                         float* __restrict__ out, int n) {
    int i    = blockIdx.x;
    int lane = threadIdx.x & 63;
    if (i >= n) return;
    int grp = lane >> 4;
    int sub = (lane >> 3) & 1;
    int fo  = (lane & 7) << 3;  // 8 features per lane
    int beg = rp[i];
    int end = rp[i + 1];
    uint4 su = *(const uint4*)(t + (size_t)i * 64 + fo);
    float dv = dinv[i];

    int deg = end - beg;
    int len = (deg + 3) >> 2;
    int gb  = beg + grp * len;
    int ge  = min(gb + len, end);

    float4 aA0 = make_float4(0.f, 0.f, 0.f, 0.f);
    float4 aA1 = aA0, aB0 = aA0, aB1 = aA0;
    for (int eb = gb; eb < ge; eb += 8) {
#pragma unroll
        for (int j = 0; j < 4; ++j) {
            int   ej = eb + 2 * j + sub;       // covers eb..eb+7 across sub
            int   ec = min(ej, end - 1);
            int   sj = cs[ec];
            uint4 u  = *(const uint4*)(t + (size_t)sj * 64 + fo);
            float m  = (ej < ge) ? 1.0f : 0.0f;
            float2 f0 = __half22float2(*(const __half2*)&u.x);
            float2 f1 = __half22float2(*(const __half2*)&u.y);
            float2 f2 = __half22float2(*(const __half2*)&u.z);
            float2 f3 = __half22float2(*(const __half2*)&u.w);
            if (j & 1) {
                aB0.x = fmaf(m, f0.x, aB0.x);
                aB0.y = fmaf(m, f0.y, aB0.y);
                aB0.z = fmaf(m, f1.x, aB0.z);
                aB0.w = fmaf(m, f1.y, aB0.w);
                aB1.x = fmaf(m, f2.x, aB1.x);
                aB1.y = fmaf(m, f2.y, aB1.y);
                aB1.z = fmaf(m, f3.x, aB1.z);
                aB1.w = fmaf(m, f3.y, aB1.w);
            } else {
                aA0.x = fmaf(m, f0.x, aA0.x);
                aA0.y = fmaf(m, f0.y, aA0.y);
                aA0.z = fmaf(m, f1.x, aA0.z);
                aA0.w = fmaf(m, f1.y, aA0.w);
                aA1.x = fmaf(m, f2.x, aA1.x);
                aA1.y = fmaf(m, f2.y, aA1.y);
                aA1.z = fmaf(m, f3.x, aA1.z);
                aA1.w = fmaf(m, f3.y, aA1.w);
            }
        }
    }
    float4 c0, c1;
    c0.x = aA0.x + aB0.x; c0.y = aA0.y + aB0.y;
    c0.z = aA0.z + aB0.z; c0.w = aA0.w + aB0.w;
    c1.x = aA1.x + aB1.x; c1.y = aA1.y + aB1.y;
    c1.z = aA1.z + aB1.z; c1.w = aA1.w + aB1.w;
    // merge sub-halves then group slices: all lanes -> full neighbor sum
#pragma unroll
    for (int s = 8; s <= 32; s <<= 1) {
        c0.x += __shfl_xor(c0.x, s, 64);
        c0.y += __shfl_xor(c0.y, s, 64);
        c0.z += __shfl_xor(c0.z, s, 64);
        c0.w += __shfl_xor(c0.w, s, 64);
        c1.x += __shfl_xor(c1.x, s, 64);
        c1.y += __shfl_xor(c1.y, s, 64);
        c1.z += __shfl_xor(c1.z, s, 64);
        c1.w += __shfl_xor(c1.w, s, 64);
    }

    float2 s0 = __half22float2(*(const __half2*)&su.x);
    float2 s1 = __half22float2(*(const __half2*)&su.y);
    float2 s2 = __half22float2(*(const __half2*)&su.z);
    float2 s3 = __half22float2(*(const __half2*)&su.w);
    float4 bv0 = *(const float4*)(bias + fo);
    float4 bv1 = *(const float4*)(bias + fo + 4);
    float4 h4a, h4b;
    h4a.x = fmaxf(fmaf(dv, c0.x + s0.x, bv0.x), 0.0f);
    h4a.y = fmaxf(fmaf(dv, c0.y + s0.y, bv0.y), 0.0f);
    h4a.z = fmaxf(fmaf(dv, c0.z + s1.x, bv0.z), 0.0f);
    h4a.w = fmaxf(fmaf(dv, c0.w + s1.y, bv0.w), 0.0f);
    h4b.x = fmaxf(fmaf(dv, c1.x + s2.x, bv1.x), 0.0f);
    h4b.y = fmaxf(fmaf(dv, c1.y + s2.y, bv1.y), 0.0f);
    h4b.z = fmaxf(fmaf(dv, c1.z + s3.x, bv1.z), 0.0f);
    h4b.w = fmaxf(fmaf(dv, c1.w + s3.y, bv1.w), 0.0f);

    // z[o] = h3 . Wl[o]: slot = lane>>3 handles o = slot and slot+8 using
    // its own 8-feature chunk; xor 1,2,4 sums over the 8 chunks.
    int slot = lane >> 3;
    const float4* wlA = (const float4*)(Wl + slot * 64 + fo);
    const float4* wlB = (const float4*)(Wl + (slot + 8) * 64 + fo);
    float4 wa0 = wlA[0], wa1 = wlA[1];
    float4 wb0 = wlB[0], wb1 = wlB[1];
    float zA = h4a.x * wa0.x + h4a.y * wa0.y + h4a.z * wa0.z + h4a.w * wa0.w +
               h4b.x * wa1.x + h4b.y * wa1.y + h4b.z * wa1.z + h4b.w * wa1.w;
    float zB = h4a.x * wb0.x + h4a.y * wb0.y + h4a.z * wb0.z + h4a.w * wb0.w +
               h4b.x * wb1.x + h4b.y * wb1.y + h4b.z * wb1.z + h4b.w * wb1.w;
#pragma unroll
    for (int s = 1; s <= 4; s <<= 1) {
        zA += __shfl_xor(zA, s, 64);
        zB += __shfl_xor(zB, s, 64);
    }
    if ((lane & 7) == 0) {
        int   b  = batch[i];
        float ic = invc[b];
        atomicAdd(out + b * 16 + slot,     zA * ic);
        atomicAdd(out + b * 16 + slot + 8, zB * ic);
    }
}

extern "C" void kernel_launch(void* const* d_in, const int* in_sizes, int n_in,
                              void* d_out, int out_size, void* d_ws, size_t ws_size,
                              hipStream_t stream) {
    const float* x    = (const float*)d_in[0];
    const int*   ei   = (const int*)d_in[1];
    const int*   batch= (const int*)d_in[2];
    const float* W1   = (const float*)d_in[3];
    const float* b1   = (const float*)d_in[4];
    const float* W2   = (const float*)d_in[5];
    const float* b2   = (const float*)d_in[6];
    const float* W3   = (const float*)d_in[7];
    const float* b3   = (const float*)d_in[8];
    const float* Wl   = (const float*)d_in[9];
    const float* bl   = (const float*)d_in[10];
    float* out = (float*)d_out;

    int n  = in_sizes[0] / 64;   // 50000 nodes
    int e  = in_sizes[1] / 2;    // 1250000 edges
    int nb = out_size / 16;      // 512 graphs

    const int* esrc = ei;
    const int* edst = ei + e;

    char* p = (char*)d_ws;
    auto carve = [&](size_t bytes) {
        char* r = p;
        p += (bytes + 255) & ~(size_t)255;
        return r;
    };
    float*  dinv  = (float*)carve((size_t)n * 4);
    int*    rp    = (int*)  carve((size_t)(n + 1) * 4);
    int*    csr   = (int*)  carve((size_t)e * 4);
    __half* tA    = (__half*)carve((size_t)n * 64 * 2);  // t1 / t3
    __half* tB    = (__half*)carve((size_t)n * 64 * 2);  // t2
    int2*   recs2 = (int2*) carve((size_t)512 * CAPB * 8);
    int*    fctr  = (int*)  carve(512 * 4);
    float*  invc  = (float*)carve((size_t)nb * 4);

    dim3 blk(256);
    dim3 blk64(64);
    int gBIN = (e + BINTILE - 1) / BINTILE;  // 306 tiles
    int gFUS = (n + 3) / 4;                  // 4 nodes / 64-thr block
    int gAGG = n;                            // 1 node / 64-thr block

    init_kernel<<<2, blk, 0, stream>>>(fctr, batch, bl, invc, out, n, nb);
    bin512_kernel<<<gBIN, blk, 0, stream>>>(esrc, edst, fctr, recs2, e, n);
    sortfill_mm_kernel<<<512, blk, 0, stream>>>(recs2, fctr, rp, dinv, csr,
                                                x, W1, tA, n);
    aggmm_kernel<<<gFUS, blk64, 0, stream>>>(tA, rp, csr, dinv, b1, W2, tB, n);
    aggmm_kernel<<<gFUS, blk64, 0, stream>>>(tB, rp, csr, dinv, b2, W3, tA, n);
    aggfinal_kernel<<<gAGG, blk64, 0, stream>>>(tA, rp, csr, dinv, b3, Wl,
                                                batch, invc, out, n);
}